// Round 5
// baseline (6342.559 us; speedup 1.0000x reference)
//
#include <hip/hip_runtime.h>
#include <hip/hip_bf16.h>

// Problem constants
#define T_LEN 2048
#define E_DIM 300
#define H_DIM 512
#define G_DIM 2048   // 4*H
#define NBLK  32     // worker blocks per direction
#define UPB   16     // hidden units per block (H/NBLK)

// Workspace layout (bytes).
// hb: (value,tag) pairs [2 dir][2 parity][2 sent][512] u64 = 16 KB
#define WS_H     0
#define WS_CLAIM 16384     // 2 u32 claim counters
#define WS_X     20480     // x: [2 sent][2048][300] f32 = 4,915,200 B
#define WS_GX    5242880   // gx: [d*2+s][2048 t][32 bb][4 q][16 ul] bf16 = 33,554,432 B

typedef float v2f __attribute__((ext_vector_type(2)));

__device__ __forceinline__ float sigmoid_fast(float x) {
    return 1.f / (1.f + __expf(-x));
}
__device__ __forceinline__ float tanh_fast(float x) {
    x = fminf(fmaxf(x, -15.f), 15.f);
    float e = __expf(-2.f * x);
    return (1.f - e) / (1.f + e);
}

// ---------------- k1: embedding gather + claim-table zero ----------------
__global__ void k_gather(const int* __restrict__ sentA, const int* __restrict__ sentB,
                         const float* __restrict__ emb, float* __restrict__ x,
                         unsigned int* __restrict__ claim) {
    const int s = blockIdx.y;
    const int* sent = s ? sentB : sentA;
    const int t0 = blockIdx.x * 16;
    if (blockIdx.x == 0 && s == 0 && threadIdx.x < 2) claim[threadIdx.x] = 0u;
    for (int idx = threadIdx.x; idx < 16 * 300; idx += 256) {
        int r = idx / 300, e = idx - r * 300;
        int t = t0 + r;
        int row = sent[t];
        x[((size_t)(s * 2048 + t)) * 300 + e] = emb[(size_t)row * 300 + e];
    }
}

// ---------------- k2: gx = x @ w_ih^T + (b_ih + b_hh), bf16, block-sliced layout ----------------
__global__ __launch_bounds__(256) void k_gemm(const float* __restrict__ x,
                                              const float* __restrict__ w_ih,
                                              const float* __restrict__ b_ih,
                                              const float* __restrict__ b_hh,
                                              __hip_bfloat16* __restrict__ gx) {
    __shared__ float xs[32 * 108];
    __shared__ float ws_[64 * 108];
    const int gi = blockIdx.x, ti = blockIdx.y, z = blockIdx.z;
    const int d = z >> 1, s = z & 1;
    const int t0 = ti * 32, g0 = gi * 64;
    const int tg = threadIdx.x & 15, tt = threadIdx.x >> 4;
    const float* wbase = w_ih + (size_t)d * G_DIM * E_DIM;

    float acc[2][4];
#pragma unroll
    for (int j = 0; j < 2; ++j)
#pragma unroll
        for (int i = 0; i < 4; ++i) acc[j][i] = 0.f;

    for (int e0 = 0; e0 < 300; e0 += 100) {
        for (int idx = threadIdx.x; idx < 32 * 25; idx += 256) {
            int r = idx / 25, c = idx - r * 25;
            float4 v = *(const float4*)(x + ((size_t)(s * 2048 + t0 + r)) * 300 + e0 + c * 4);
            *(float4*)&xs[r * 108 + c * 4] = v;
        }
        for (int idx = threadIdx.x; idx < 64 * 25; idx += 256) {
            int r = idx / 25, c = idx - r * 25;
            float4 v = *(const float4*)(wbase + (size_t)(g0 + r) * 300 + e0 + c * 4);
            *(float4*)&ws_[r * 108 + c * 4] = v;
        }
        __syncthreads();

        for (int c = 0; c < 25; ++c) {
            float4 xv[2], wv[4];
#pragma unroll
            for (int j = 0; j < 2; ++j) xv[j] = *(const float4*)&xs[(tt + 16 * j) * 108 + c * 4];
#pragma unroll
            for (int i = 0; i < 4; ++i) wv[i] = *(const float4*)&ws_[(tg + 16 * i) * 108 + c * 4];
#pragma unroll
            for (int j = 0; j < 2; ++j)
#pragma unroll
                for (int i = 0; i < 4; ++i)
                    acc[j][i] += xv[j].x * wv[i].x + xv[j].y * wv[i].y +
                                 xv[j].z * wv[i].z + xv[j].w * wv[i].w;
        }
        __syncthreads();
    }

#pragma unroll
    for (int i = 0; i < 4; ++i) {
        int g = g0 + tg + 16 * i;
        float bias = b_ih[d * G_DIM + g] + b_hh[d * G_DIM + g];
        int pos = ((g >> 4) & 31) * 64 + (g >> 9) * 16 + (g & 15);
#pragma unroll
        for (int j = 0; j < 2; ++j) {
            int t = t0 + tt + 16 * j;
            int tout = d ? (T_LEN - 1 - t) : t;
            float v = acc[j][i] + bias;
            gx[(((size_t)(d * 2 + s) * T_LEN + tout) << 11) + pos] = __float2bfloat16(v);
        }
    }
}

// ---------------- k3: recurrent LSTM, XCD-pinned workers, L2-atomic handshake ----------------
// Blocks claim worker slots by physical XCD (XCD0 -> dir 0, XCD1 -> dir 1, 32 each;
// others exit). h exchanged as tagged (value,step) u64 packets via atomics that
// EXECUTE IN THE XCD-LOCAL L2: poll = atomic_or(0) with return (sc0), publish =
// atomic_swap. Atomics are never served by L1 (R4's failure mode), and without
// sc1 they stay at the XCD L2 coherence point. 88 KB LDS -> 1 block/CU.
__global__ __launch_bounds__(256, 1) void k_rnn(const float* __restrict__ w_hh,
                                                const __hip_bfloat16* __restrict__ gx,
                                                unsigned long long* __restrict__ hb,
                                                unsigned int* __restrict__ claim) {
    unsigned int xcc;
    asm("s_getreg_b32 %0, hwreg(HW_REG_XCC_ID)" : "=s"(xcc));
    xcc &= 7u;
    if (xcc > 1u) return;

    __shared__ float hlds[2 * H_DIM];    // 4 KB
    __shared__ float pacc[128 * 68];     // 34 KB
    __shared__ float big_pad[12288];     // 48 KB occupancy limiter -> 1 block/CU
    __shared__ unsigned int slot_s;

    const int tid = threadIdx.x;
    ((volatile float*)big_pad)[tid] = 0.f;   // keep pad allocated

    if (tid == 0) slot_s = atomicAdd(&claim[xcc], 1u);
    __syncthreads();
    const unsigned int slot = slot_s;
    if (slot >= NBLK) return;

    const int d = (int)xcc;
    const int bb = (int)slot;
    const int lane = tid & 63;
    const int w = tid >> 6;
    // reduce/gate identity: physical pacc row r = tid>>1 = (s*16+ul)*4 + q
    const int r_g  = tid >> 1;
    const int half = tid & 1;
    const int q_g  = r_g & 3;
    const int ul_g = (r_g >> 2) & 15;
    const int s_g  = r_g >> 6;

    // persistent weights, row-paired: wreg2[r2][kb] = { W[w*512+bb*16+2r2][k], W[+1][k] }
    v2f wreg2[8][8];
#pragma unroll
    for (int r2 = 0; r2 < 8; ++r2)
#pragma unroll
        for (int kb = 0; kb < 8; ++kb) {
            const float* wp = w_hh + ((size_t)d * G_DIM + w * 512 + bb * 16 + 2 * r2) * H_DIM
                            + kb * 64 + lane;
            v2f t2; t2.x = wp[0]; t2.y = wp[H_DIM];
            wreg2[r2][kb] = t2;
        }

    float c_state = 0.f;

    // h_0 = 0, tag 0, parity 0 (atomic swap -> executes in XCD L2)
    if ((lane & 7) == 0) {
        unsigned long long* dst = hb + ((size_t)(d * 2 + 0) * 2 + s_g) * H_DIM + bb * UPB + ul_g;
        unsigned long long z = 0ull;
        asm volatile("global_atomic_swap_x2 %0, %1, off" :: "v"(dst), "v"(z) : "memory");
    }

    // gx prefetch pipeline (1 step ahead)
    const __hip_bfloat16* gxp = gx + (((size_t)(d * 2 + s_g) * T_LEN) << 11)
                              + bb * 64 + q_g * 16 + ul_g;
    float gx_cur = (float)gxp[0];

    int budget = 1 << 21;   // cumulative poll budget: deadlock -> bounded wrong exit, no hang
    const unsigned long long zero64 = 0ull;

    for (int t = 0; t < T_LEN; ++t) {
        const int p = t & 1;
        const int pn = (t + 1) & 1;
        unsigned long long* hbp = hb + ((size_t)(d * 2 + p) * 2) * H_DIM;
        unsigned long long* p0 = hbp + w * 128 + lane;          // sent 0
        unsigned long long* p1 = p0 + H_DIM;                    // sent 1 (+4096 B)
        const unsigned int tag = (unsigned int)t;
        unsigned long long a0, a1, a2, a3;

        // poll this wave's k-quarter via L2-executing atomic reads (never L1)
        for (;;) {
            asm volatile(
                "global_atomic_or_x2 %0, %4, %6, off sc0\n\t"
                "global_atomic_or_x2 %1, %4, %6, off offset:512 sc0\n\t"
                "global_atomic_or_x2 %2, %5, %6, off sc0\n\t"
                "global_atomic_or_x2 %3, %5, %6, off offset:512 sc0\n\t"
                "s_waitcnt vmcnt(0)"
                : "=v"(a0), "=v"(a1), "=v"(a2), "=v"(a3)
                : "v"(p0), "v"(p1), "v"(zero64)
                : "memory");
            bool ok = ((unsigned int)(a0 >> 32) == tag) & ((unsigned int)(a1 >> 32) == tag)
                    & ((unsigned int)(a2 >> 32) == tag) & ((unsigned int)(a3 >> 32) == tag);
            if (__all(ok)) break;
            if (--budget < 0) break;
        }

        // stage this wave's quarter into LDS
        const int i0 = w * 128 + lane;
        hlds[i0]            = __uint_as_float((unsigned int)a0);
        hlds[i0 + 64]       = __uint_as_float((unsigned int)a1);
        hlds[512 + i0]      = __uint_as_float((unsigned int)a2);
        hlds[512 + i0 + 64] = __uint_as_float((unsigned int)a3);
        __syncthreads();   // B1

        // prefetch next step's gate input (completes during compute)
        float gx_nxt = (t + 1 < T_LEN) ? (float)gxp[(size_t)(t + 1) << 11] : 0.f;

        // full h fragment for this lane
        float hv[2][8];
#pragma unroll
        for (int s = 0; s < 2; ++s)
#pragma unroll
            for (int kb = 0; kb < 8; ++kb)
                hv[s][kb] = hlds[s * H_DIM + kb * 64 + lane];

        // matvec partials: 8 row-pairs x 2 sentences per lane, packed fp32 FMA
        v2f acc2[8][2];
#pragma unroll
        for (int r2 = 0; r2 < 8; ++r2) {
            acc2[r2][0] = (v2f)(0.f);
            acc2[r2][1] = (v2f)(0.f);
        }
#pragma unroll
        for (int kb = 0; kb < 8; ++kb) {
#pragma unroll
            for (int s = 0; s < 2; ++s) {
                float h0 = hv[s][kb];
                v2f h2; h2.x = h0; h2.y = h0;
#pragma unroll
                for (int r2 = 0; r2 < 8; ++r2)
                    acc2[r2][s] += wreg2[r2][kb] * h2;
            }
        }

        // publish partials; pacc row = (s*16 + unit)*4 + gate(w)  -> conflict-free reduce
#pragma unroll
        for (int r2 = 0; r2 < 8; ++r2)
#pragma unroll
            for (int s = 0; s < 2; ++s) {
                pacc[((s * 16 + 2 * r2 + 0) * 4 + w) * 68 + lane] = acc2[r2][s].x;
                pacc[((s * 16 + 2 * r2 + 1) * 4 + w) * 68 + lane] = acc2[r2][s].y;
            }
        __syncthreads();   // B2

        // reduce physical row r_g = tid>>1 (2 threads x 32 values, R2's 0-conflict pattern)
        const float4* pr = (const float4*)&pacc[r_g * 68 + half * 32];
        float4 sv = pr[0];
#pragma unroll
        for (int j2 = 1; j2 < 8; ++j2) {
            float4 q4 = pr[j2];
            sv.x += q4.x; sv.y += q4.y; sv.z += q4.z; sv.w += q4.w;
        }
        float v = (sv.x + sv.y) + (sv.z + sv.w);
        v += __shfl_xor(v, 1, 64);
        v += gx_cur;
        float act = (q_g == 2) ? tanh_fast(v) : sigmoid_fast(v);

        // gather i/f/g/o within the 8-lane group (gates of one unit are adjacent)
        const int g0l = lane & ~7;
        float si  = __shfl(act, g0l + 0, 64);
        float sf  = __shfl(act, g0l + 2, 64);
        float tgg = __shfl(act, g0l + 4, 64);
        float so  = __shfl(act, g0l + 6, 64);
        if ((lane & 7) == 0) {
            c_state = sf * c_state + si * tgg;
            float h_new = so * tanh_fast(c_state);
            unsigned long long pkt = ((unsigned long long)(unsigned int)(t + 1) << 32)
                                   | (unsigned long long)__float_as_uint(h_new);
            unsigned long long* dst = hb + ((size_t)(d * 2 + pn) * 2 + s_g) * H_DIM
                                    + bb * UPB + ul_g;
            asm volatile("global_atomic_swap_x2 %0, %1, off" :: "v"(dst), "v"(pkt) : "memory");
        }
        gx_cur = gx_nxt;
    }
}

// ---------------- k4: head ----------------
__global__ __launch_bounds__(512) void k_head(const unsigned long long* __restrict__ hb,
                                              const float* __restrict__ bi_w,
                                              const float* __restrict__ bi_b,
                                              const float* __restrict__ blA,
                                              const float* __restrict__ blB,
                                              const float* __restrict__ bl_b,
                                              const float* __restrict__ out_w,
                                              const float* __restrict__ out_b,
                                              float* __restrict__ out) {
    __shared__ float enc[2][512];
    __shared__ float red[8];
    const int tid = threadIdx.x;
    const float bw0 = bi_w[0], bw1 = bi_w[1], bib = bi_b[0];
    {
        int u = tid;
        float hfA = __uint_as_float((unsigned int)hb[((0 * 2 + 0) * 2 + 0) * 512 + u]);
        float hbA = __uint_as_float((unsigned int)hb[((1 * 2 + 0) * 2 + 0) * 512 + u]);
        float hfB = __uint_as_float((unsigned int)hb[((0 * 2 + 0) * 2 + 1) * 512 + u]);
        float hbB = __uint_as_float((unsigned int)hb[((1 * 2 + 0) * 2 + 1) * 512 + u]);
        enc[0][u] = bw0 * hfA + bw1 * hbA + bib;
        enc[1][u] = bw0 * hfB + bw1 * hbB + bib;
    }
    __syncthreads();
    const int j = tid;
    float acc = bl_b[j];
#pragma unroll 4
    for (int u = 0; u < 512; ++u)
        acc += enc[0][u] * blA[u * 512 + j] + enc[1][u] * blB[u * 512 + j];
    float contrib = tanh_fast(acc) * out_w[j];
#pragma unroll
    for (int m = 1; m < 64; m <<= 1) contrib += __shfl_xor(contrib, m, 64);
    if ((tid & 63) == 0) red[tid >> 6] = contrib;
    __syncthreads();
    if (tid == 0) {
        float s = 0.f;
#pragma unroll
        for (int i = 0; i < 8; ++i) s += red[i];
        s += out_b[0];
        out[0] = sigmoid_fast(s);
    }
}

extern "C" void kernel_launch(void* const* d_in, const int* in_sizes, int n_in,
                              void* d_out, int out_size, void* d_ws, size_t ws_size,
                              hipStream_t stream) {
    const int*   sentA = (const int*)d_in[0];
    const int*   sentB = (const int*)d_in[1];
    // d_in[2] = hidden (unused by forward)
    const float* emb   = (const float*)d_in[3];
    const float* w_ih  = (const float*)d_in[4];
    const float* w_hh  = (const float*)d_in[5];
    const float* b_ih  = (const float*)d_in[6];
    const float* b_hh  = (const float*)d_in[7];
    const float* bi_w  = (const float*)d_in[8];
    const float* bi_b  = (const float*)d_in[9];
    const float* blA   = (const float*)d_in[10];
    const float* blB   = (const float*)d_in[11];
    const float* bl_b  = (const float*)d_in[12];
    const float* out_w = (const float*)d_in[13];
    const float* out_b = (const float*)d_in[14];
    float* out = (float*)d_out;

    char* ws = (char*)d_ws;
    unsigned long long* hbf   = (unsigned long long*)(ws + WS_H);
    unsigned int*       claim = (unsigned int*)(ws + WS_CLAIM);
    float*              x     = (float*)(ws + WS_X);
    __hip_bfloat16*     gx    = (__hip_bfloat16*)(ws + WS_GX);

    k_gather<<<dim3(128, 2), 256, 0, stream>>>(sentA, sentB, emb, x, claim);
    k_gemm<<<dim3(32, 64, 4), 256, 0, stream>>>(x, w_ih, b_ih, b_hh, gx);
    k_rnn<<<dim3(1024), 256, 0, stream>>>(w_hh, gx, hbf, claim);
    k_head<<<dim3(1), 512, 0, stream>>>(hbf, bi_w, bi_b, blA, blB, bl_b, out_w, out_b, out);
}